// Round 7
// baseline (220.070 us; speedup 1.0000x reference)
//
#include <hip/hip_runtime.h>

typedef __attribute__((ext_vector_type(8))) __bf16 bf16x8;
typedef __attribute__((ext_vector_type(8))) unsigned short ushort8;
typedef __attribute__((ext_vector_type(4))) float f32x4;

constexpr int C_ = 32, NN = 64;
constexpr int PK = 3375;              // 15^3
constexpr int K_TOT = 108000;         // C*PK
constexpr int F_TOT = 1024;
constexpr int M_TOT = 128;            // B*N
constexpr int KSTEPS = 3375;          // K_TOT/32

// GEMM LDS geometry: W tile 32k x 128f fp32 stored as 16 row-pairs of
// (1024 data + 16 pad) bytes -> strided B-column reads are 2-way (free).
constexpr int WPAIR  = 1040;
constexpr int WBUF   = 16 * WPAIR;    // 16640
constexpr int ABUF   = 8192;          // 32k x 128m bf16 fragment-ordered

__device__ __forceinline__ unsigned short f2bf(float f) {
    unsigned int b = __builtin_bit_cast(unsigned int, f);
    b += 0x7FFFu + ((b >> 16) & 1u);      // round-to-nearest-even
    return (unsigned short)(b >> 16);
}

// async 16B global -> LDS. LDS base must be wave-uniform (HW writes lane i at
// base + i*16); global address is per-lane (m173).
__device__ __forceinline__ void async_copy16(void* lds, const void* g) {
    __builtin_amdgcn_global_load_lds(
        (const __attribute__((address_space(1))) unsigned int*)g,
        (__attribute__((address_space(3))) unsigned int*)lds, 16, 0, 0);
}

// ---------------- kernel 1: patch gather -> bf16 A in MFMA-FRAGMENT order --------
// Af layout: [step 0..3374][mt 0..7][lane 0..63][e 0..7] bf16, value at
// (st, mt, lane=lgrp*16+fr, e) = A[m = fr + mt*16][k = st*32 + lgrp*8 + e].
// NOTE (R7): launched TWICE this round as a timing probe (idempotent).
__global__ void extract_kernel(const float* __restrict__ x,
                               const int* __restrict__ cent,
                               unsigned short* __restrict__ Af) {
    int m = blockIdx.x;            // 0..127  (b*64+n)
    int c = blockIdx.y;            // 0..31
    int b = m >> 6, n = m & 63;
    int mt = m >> 4, fr = m & 15;
    int cx = cent[(b * NN + n) * 3 + 0];
    int cy = cent[(b * NN + n) * 3 + 1];
    int cz = cent[(b * NN + n) * 3 + 2];
    int sx = max(cx - 7, 0), ex = min(cx + 8, 96);
    int sy = max(cy - 7, 0), ey = min(cy + 8, 96);
    int sz = max(cz - 7, 0), ez = min(cz + 8, 96);
    const float* xb = x + (size_t)(b * C_ + c) * (96 * 96 * 96);
    for (int k = threadIdx.x; k < PK; k += blockDim.x) {
        int iz = k % 15;
        int t  = k / 15;
        int iy = t % 15;
        int ix = t / 15;
        int hx = sx + ix, wy = sy + iy, dz = sz + iz;
        float v = 0.0f;
        if (hx < ex && wy < ey && dz < ez)
            v = xb[(hx * 96 + wy) * 96 + dz];
        int K  = c * PK + k;
        int st = K >> 5, kr = K & 31;
        int lg = kr >> 3, e = kr & 7;
        size_t off = (size_t)st * 4096 + (size_t)mt * 512 + (size_t)(lg * 16 + fr) * 8 + e;
        Af[off] = f2bf(v);
    }
}

// ---------------- kernel 2: split-K GEMM, dbuf LDS (W+A) + counted vmcnt ---------
// (unchanged from R6)
__global__ __launch_bounds__(256, 3) void gemm_kernel(const unsigned short* __restrict__ Af,
                                                      const float* __restrict__ W,
                                                      float* __restrict__ partial,
                                                      int CS) {
    __shared__ __align__(16) unsigned char smem[2 * WBUF + 2 * ABUF];  // 49,664 B
    int fx, s;
    if (gridDim.y == 64) {                     // bijective XCD swizzle (512 = 8*64)
        int id = blockIdx.y * 8 + blockIdx.x;
        int xcd = id & 7, q = id >> 3;
        s  = xcd * 8 + (q & 7);                // chunk s pinned to one XCD
        fx = q >> 3;
    } else { fx = blockIdx.x; s = blockIdx.y; }
    int st0 = s * CS;
    int st1 = min(st0 + CS, KSTEPS);
    int f0  = fx * 128;

    int tid  = (int)threadIdx.x;
    int wave = tid >> 6, lane = tid & 63;
    int fr = lane & 15, lgrp = lane >> 4;
    int row2 = lane >> 5;                      // which row of a 2-row pair
    int col4 = (lane & 31) << 2;               // fp32 col group (16B)

    f32x4 acc[8][2];
#pragma unroll
    for (int i = 0; i < 8; ++i)
#pragma unroll
        for (int j = 0; j < 2; ++j) acc[i][j] = (f32x4)(0.0f);

    auto STAGE = [&](int buf, int st) {
        unsigned char* wb = smem + buf * WBUF;
        const float* wsrc = W + ((size_t)st * 32 + row2) * F_TOT + f0 + col4;
#pragma unroll
        for (int r = 0; r < 4; ++r) {
            int pair = r * 4 + wave;
            async_copy16(wb + pair * WPAIR, wsrc + (size_t)(pair * 2) * F_TOT);
        }
        unsigned char* ab = smem + 2 * WBUF + buf * ABUF + wave * 2048;
        const unsigned char* ag = (const unsigned char*)Af + (size_t)st * 8192
                                + wave * 2048 + lane * 16;
        async_copy16(ab,        ag);
        async_copy16(ab + 1024, ag + 1024);
    };

    auto COMPUTE = [&](int buf) {
        const unsigned char* ab = smem + 2 * WBUF + buf * ABUF;
        const unsigned char* wb = smem + buf * WBUF;
        bf16x8 afrag[8];
#pragma unroll
        for (int mt = 0; mt < 8; ++mt)
            afrag[mt] = *reinterpret_cast<const bf16x8*>(ab + mt * 1024 + lane * 16);
#pragma unroll
        for (int ft = 0; ft < 2; ++ft) {
            int fl4 = (wave * 32 + ft * 16 + fr) * 4;
            float wv[8];
#pragma unroll
            for (int j = 0; j < 8; ++j) {
                int row = lgrp * 8 + j;
                wv[j] = *reinterpret_cast<const float*>(
                            wb + (row >> 1) * WPAIR + (row & 1) * 512 + fl4);
            }
            ushort8 bt;
#pragma unroll
            for (int j = 0; j < 8; ++j) bt[j] = f2bf(wv[j]);
            bf16x8 bfrag = __builtin_bit_cast(bf16x8, bt);
#pragma unroll
            for (int mt = 0; mt < 8; ++mt)
                acc[mt][ft] = __builtin_amdgcn_mfma_f32_16x16x32_bf16(afrag[mt], bfrag, acc[mt][ft], 0, 0, 0);
        }
    };

    int cur = 0;
    STAGE(0, st0);
    for (int t = st0; t < st1 - 1; ++t) {
        STAGE(cur ^ 1, t + 1);
        asm volatile("s_waitcnt vmcnt(6)" ::: "memory");
        __builtin_amdgcn_s_barrier();
        COMPUTE(cur);
        __builtin_amdgcn_s_barrier();
        cur ^= 1;
    }
    asm volatile("s_waitcnt vmcnt(0)" ::: "memory");
    __builtin_amdgcn_s_barrier();
    COMPUTE(cur);

    float* pout = partial + (size_t)s * (M_TOT * F_TOT);
#pragma unroll
    for (int mt = 0; mt < 8; ++mt) {
        int mbase = mt * 16 + lgrp * 4;
#pragma unroll
        for (int ft = 0; ft < 2; ++ft) {
            int f = f0 + wave * 32 + ft * 16 + fr;
#pragma unroll
            for (int r = 0; r < 4; ++r)
                pout[(size_t)(mbase + r) * F_TOT + f] = acc[mt][ft][r];
        }
    }
}

// ---------------- kernel 3: split-K reduce + bias (vectorized) ----------------
__global__ void reduce_kernel(const float* __restrict__ partial,
                              const float* __restrict__ bias,
                              float* __restrict__ out, int S) {
    int i4 = (blockIdx.x * blockDim.x + threadIdx.x) * 4;
    if (i4 >= M_TOT * F_TOT) return;
    f32x4 a = *reinterpret_cast<const f32x4*>(bias + (i4 & (F_TOT - 1)));
    for (int s = 0; s < S; ++s)
        a += *reinterpret_cast<const f32x4*>(partial + (size_t)s * (M_TOT * F_TOT) + i4);
    *reinterpret_cast<f32x4*>(out + i4) = a;
}

extern "C" void kernel_launch(void* const* d_in, const int* in_sizes, int n_in,
                              void* d_out, int out_size, void* d_ws, size_t ws_size,
                              hipStream_t stream) {
    const float* x    = (const float*)d_in[0];
    const int*   cent = (const int*)d_in[1];
    const float* W    = (const float*)d_in[2];
    const float* bias = (const float*)d_in[3];
    float* out = (float*)d_out;

    unsigned short* Af = (unsigned short*)d_ws;
    size_t Af_bytes = (size_t)KSTEPS * 4096 * 2;                 // 27,648,000
    float* partial = (float*)((char*)d_ws + Af_bytes);

    size_t avail = ws_size > Af_bytes ? ws_size - Af_bytes : 0;
    int S = (int)(avail / ((size_t)M_TOT * F_TOT * 4));
    if (S > 64) S = 64;                   // grid 8x64 = 512 blocks
    if (S < 1)  S = 1;
    int CS = (KSTEPS + S - 1) / S;        // 53 for S=64
    S = (KSTEPS + CS - 1) / CS;           // 64 (last chunk = 36 steps)

    // --- R7 TIMING PROBE: extract launched twice (idempotent, deterministic).
    // dur_us(R7) - dur_us(R6) = extract's true duration E. Branch: E large ->
    // optimize extract; E small -> GEMM W-stream DRAM efficiency is the pig.
    extract_kernel<<<dim3(M_TOT, C_), 256, 0, stream>>>(x, cent, Af);
    extract_kernel<<<dim3(M_TOT, C_), 256, 0, stream>>>(x, cent, Af);
    gemm_kernel<<<dim3(8, S), 256, 0, stream>>>(Af, W, partial, CS);
    reduce_kernel<<<dim3((M_TOT * F_TOT + 1023) / 1024, 1, 1), 256, 0, stream>>>(partial, bias, out, S);
}

// Round 8
// 152.365 us; speedup vs baseline: 1.4444x; 1.4444x over previous
//
#include <hip/hip_runtime.h>

typedef __attribute__((ext_vector_type(8))) __bf16 bf16x8;
typedef __attribute__((ext_vector_type(8))) unsigned short ushort8;
typedef __attribute__((ext_vector_type(4))) float f32x4;

constexpr int C_ = 32, NN = 64;
constexpr int PK = 3375;              // 15^3
constexpr int K_TOT = 108000;         // C*PK
constexpr int F_TOT = 1024;
constexpr int M_TOT = 128;            // B*N
constexpr int KSTEPS = 3375;          // K_TOT/32

// GEMM LDS geometry: W tile 32k x 128f fp32 stored as 16 row-pairs of
// (1024 data + 16 pad) bytes -> strided B-column reads are 2-way (free).
constexpr int WPAIR  = 1040;
constexpr int WBUF   = 16 * WPAIR;    // 16640
constexpr int ABUF   = 8192;          // 32k x 128m bf16, fragment-ordered in LDS

__device__ __forceinline__ unsigned short f2bf(float f) {
    unsigned int b = __builtin_bit_cast(unsigned int, f);
    b += 0x7FFFu + ((b >> 16) & 1u);      // round-to-nearest-even
    return (unsigned short)(b >> 16);
}

// async 16B global -> LDS. LDS dest: wave-uniform base, HW writes lane i at
// base + i*16. Global source address is PER-LANE (m173) -> gather swizzle free.
__device__ __forceinline__ void async_copy16(void* lds, const void* g) {
    __builtin_amdgcn_global_load_lds(
        (const __attribute__((address_space(1))) unsigned int*)g,
        (__attribute__((address_space(3))) unsigned int*)lds, 16, 0, 0);
}

// ---------------- kernel 1: patch gather -> bf16 A natural [m][K] layout ---------
// Per (m,c) block writes Af[m*K_TOT + c*PK .. +PK) -- fully contiguous/coalesced
// (fragment gathering is deferred to GEMM's per-lane global_load_lds sources).
__global__ void extract_kernel(const float* __restrict__ x,
                               const int* __restrict__ cent,
                               unsigned short* __restrict__ Af) {
    int m = blockIdx.x;            // 0..127  (b*64+n)
    int c = blockIdx.y;            // 0..31
    int b = m >> 6, n = m & 63;
    int cx = cent[(b * NN + n) * 3 + 0];
    int cy = cent[(b * NN + n) * 3 + 1];
    int cz = cent[(b * NN + n) * 3 + 2];
    int sx = max(cx - 7, 0), ex = min(cx + 8, 96);
    int sy = max(cy - 7, 0), ey = min(cy + 8, 96);
    int sz = max(cz - 7, 0), ez = min(cz + 8, 96);
    const float* xb = x + (size_t)(b * C_ + c) * (96 * 96 * 96);
    unsigned short* Arow = Af + (size_t)m * K_TOT + (size_t)c * PK;
    for (int k = threadIdx.x; k < PK; k += blockDim.x) {
        int iz = k % 15;
        int t  = k / 15;
        int iy = t % 15;
        int ix = t / 15;
        int hx = sx + ix, wy = sy + iy, dz = sz + iz;
        float v = 0.0f;
        if (hx < ex && wy < ey && dz < ez)
            v = xb[(hx * 96 + wy) * 96 + dz];
        Arow[k] = f2bf(v);
    }
}

// ---------------- kernel 2: split-K GEMM, dbuf LDS (W+A) + counted vmcnt ---------
// Tile: M=128 x F=128, k-step 32, 4 waves. W staged linearly; A staged via
// per-lane gather sources (row m = fr + mt*16, 16B at k0 + lgrp*8) into the
// fragment-ordered LDS layout. 6 load_lds per wave per step; steady-state wait
// vmcnt(6) keeps the next step's loads in flight across the barrier.
__global__ __launch_bounds__(256, 3) void gemm_kernel(const unsigned short* __restrict__ Af,
                                                      const float* __restrict__ W,
                                                      float* __restrict__ partial,
                                                      int CS) {
    __shared__ __align__(16) unsigned char smem[2 * WBUF + 2 * ABUF];  // 49,664 B
    int fx, s;
    if (gridDim.y == 64) {                     // bijective XCD swizzle (512 = 8*64)
        int id = blockIdx.y * 8 + blockIdx.x;
        int xcd = id & 7, q = id >> 3;
        s  = xcd * 8 + (q & 7);                // all 8 fx-blocks of chunk s -> one XCD
        fx = q >> 3;
    } else { fx = blockIdx.x; s = blockIdx.y; }
    int st0 = s * CS;
    int st1 = min(st0 + CS, KSTEPS);
    int f0  = fx * 128;

    int tid  = (int)threadIdx.x;
    int wave = tid >> 6, lane = tid & 63;
    int fr = lane & 15, lgrp = lane >> 4;
    int row2 = lane >> 5;                      // which row of a 2-row pair
    int col4 = (lane & 31) << 2;               // fp32 col group (16B)

    f32x4 acc[8][2];
#pragma unroll
    for (int i = 0; i < 8; ++i)
#pragma unroll
        for (int j = 0; j < 2; ++j) acc[i][j] = (f32x4)(0.0f);

    // per wave per step: 4 W row-pairs (linear) + 2 A fragment-gathers
    auto STAGE = [&](int buf, int st) {
        int k0 = st << 5;
        unsigned char* wb = smem + buf * WBUF;
        const float* wsrc = W + ((size_t)st * 32 + row2) * F_TOT + f0 + col4;
#pragma unroll
        for (int r = 0; r < 4; ++r) {
            int pair = r * 4 + wave;
            async_copy16(wb + pair * WPAIR, wsrc + (size_t)(pair * 2) * F_TOT);
        }
        unsigned char* ab = smem + 2 * WBUF + buf * ABUF;
        const unsigned short* ag = Af + (size_t)fr * K_TOT + k0 + lgrp * 8;
#pragma unroll
        for (int i = 0; i < 2; ++i) {
            int mt = wave * 2 + i;
            async_copy16(ab + mt * 1024, ag + (size_t)(mt * 16) * K_TOT);
        }
    };

    auto COMPUTE = [&](int buf) {
        const unsigned char* ab = smem + 2 * WBUF + buf * ABUF;
        const unsigned char* wb = smem + buf * WBUF;
        bf16x8 afrag[8];
#pragma unroll
        for (int mt = 0; mt < 8; ++mt)      // ds_read_b128, lane-consecutive 16B
            afrag[mt] = *reinterpret_cast<const bf16x8*>(ab + mt * 1024 + lane * 16);
#pragma unroll
        for (int ft = 0; ft < 2; ++ft) {
            int fl4 = (wave * 32 + ft * 16 + fr) * 4;
            float wv[8];
#pragma unroll
            for (int j = 0; j < 8; ++j) {
                int row = lgrp * 8 + j;
                wv[j] = *reinterpret_cast<const float*>(
                            wb + (row >> 1) * WPAIR + (row & 1) * 512 + fl4);
            }
            ushort8 bt;
#pragma unroll
            for (int j = 0; j < 8; ++j) bt[j] = f2bf(wv[j]);
            bf16x8 bfrag = __builtin_bit_cast(bf16x8, bt);
#pragma unroll
            for (int mt = 0; mt < 8; ++mt)
                acc[mt][ft] = __builtin_amdgcn_mfma_f32_16x16x32_bf16(afrag[mt], bfrag, acc[mt][ft], 0, 0, 0);
        }
    };

    int cur = 0;
    STAGE(0, st0);
    for (int t = st0; t < st1 - 1; ++t) {
        STAGE(cur ^ 1, t + 1);
        asm volatile("s_waitcnt vmcnt(6)" ::: "memory");  // own stage(t) done; stage(t+1) in flight
        __builtin_amdgcn_s_barrier();
        COMPUTE(cur);
        __builtin_amdgcn_s_barrier();
        cur ^= 1;
    }
    asm volatile("s_waitcnt vmcnt(0)" ::: "memory");
    __builtin_amdgcn_s_barrier();
    COMPUTE(cur);

    // --- write partials: D row = lgrp*4 + r, col = fr (m89-verified mapping) ---
    float* pout = partial + (size_t)s * (M_TOT * F_TOT);
#pragma unroll
    for (int mt = 0; mt < 8; ++mt) {
        int mbase = mt * 16 + lgrp * 4;
#pragma unroll
        for (int ft = 0; ft < 2; ++ft) {
            int f = f0 + wave * 32 + ft * 16 + fr;
#pragma unroll
            for (int r = 0; r < 4; ++r)
                pout[(size_t)(mbase + r) * F_TOT + f] = acc[mt][ft][r];
        }
    }
}

// ---------------- kernel 3: split-K reduce + bias (vectorized) ----------------
__global__ void reduce_kernel(const float* __restrict__ partial,
                              const float* __restrict__ bias,
                              float* __restrict__ out, int S) {
    int i4 = (blockIdx.x * blockDim.x + threadIdx.x) * 4;
    if (i4 >= M_TOT * F_TOT) return;
    f32x4 a = *reinterpret_cast<const f32x4*>(bias + (i4 & (F_TOT - 1)));
    for (int s = 0; s < S; ++s)
        a += *reinterpret_cast<const f32x4*>(partial + (size_t)s * (M_TOT * F_TOT) + i4);
    *reinterpret_cast<f32x4*>(out + i4) = a;
}

extern "C" void kernel_launch(void* const* d_in, const int* in_sizes, int n_in,
                              void* d_out, int out_size, void* d_ws, size_t ws_size,
                              hipStream_t stream) {
    const float* x    = (const float*)d_in[0];
    const int*   cent = (const int*)d_in[1];
    const float* W    = (const float*)d_in[2];
    const float* bias = (const float*)d_in[3];
    float* out = (float*)d_out;

    unsigned short* Af = (unsigned short*)d_ws;
    size_t Af_bytes = (size_t)M_TOT * K_TOT * 2;                 // 27,648,000
    float* partial = (float*)((char*)d_ws + Af_bytes);

    size_t avail = ws_size > Af_bytes ? ws_size - Af_bytes : 0;
    int S = (int)(avail / ((size_t)M_TOT * F_TOT * 4));
    if (S > 64) S = 64;                   // grid 8x64 = 512 blocks = 2/CU
    if (S < 1)  S = 1;
    int CS = (KSTEPS + S - 1) / S;        // 53 for S=64
    S = (KSTEPS + CS - 1) / CS;           // 64 (last chunk = 36 steps)

    extract_kernel<<<dim3(M_TOT, C_), 256, 0, stream>>>(x, cent, Af);
    gemm_kernel<<<dim3(8, S), 256, 0, stream>>>(Af, W, partial, CS);
    reduce_kernel<<<dim3((M_TOT * F_TOT + 1023) / 1024, 1, 1), 256, 0, stream>>>(partial, bias, out, S);
}

// Round 9
// 143.596 us; speedup vs baseline: 1.5326x; 1.0611x over previous
//
#include <hip/hip_runtime.h>

typedef __attribute__((ext_vector_type(8))) __bf16 bf16x8;
typedef __attribute__((ext_vector_type(8))) unsigned short ushort8;
typedef __attribute__((ext_vector_type(4))) float f32x4;

constexpr int C_ = 32, NN = 64;
constexpr int PK = 3375;              // 15^3
constexpr int K_TOT = 108000;         // C*PK
constexpr int F_TOT = 1024;
constexpr int M_TOT = 128;            // B*N
constexpr int KSTEPS = 3375;          // K_TOT/32

// GEMM LDS geometry (F-tile 256): W tile 32k x 256f fp32 stored as 16 row-PAIRS
// of (2048 data + 16 pad) bytes. B-column reads: lgrp stride = 4 pairs = 2064*4 B
// = 16 banks apart -> 2-way aliasing (free, m136); async dests stay 16B-aligned.
constexpr int WPAIR  = 2064;
constexpr int WBUF   = 16 * WPAIR;    // 33,024
constexpr int ABUF   = 8192;          // 32k x 128m bf16, fragment-ordered in LDS

__device__ __forceinline__ unsigned short f2bf(float f) {
    unsigned int b = __builtin_bit_cast(unsigned int, f);
    b += 0x7FFFu + ((b >> 16) & 1u);      // round-to-nearest-even
    return (unsigned short)(b >> 16);
}

// async 16B global -> LDS. LDS dest: wave-uniform base, HW writes lane i at
// base + i*16. Global source address is PER-LANE (m173) -> gather swizzle free.
__device__ __forceinline__ void async_copy16(void* lds, const void* g) {
    __builtin_amdgcn_global_load_lds(
        (const __attribute__((address_space(1))) unsigned int*)g,
        (__attribute__((address_space(3))) unsigned int*)lds, 16, 0, 0);
}

// ---------------- kernel 1: patch gather -> bf16 A natural [m][K] layout ---------
__global__ void extract_kernel(const float* __restrict__ x,
                               const int* __restrict__ cent,
                               unsigned short* __restrict__ Af) {
    int m = blockIdx.x;            // 0..127  (b*64+n)
    int c = blockIdx.y;            // 0..31
    int b = m >> 6, n = m & 63;
    int cx = cent[(b * NN + n) * 3 + 0];
    int cy = cent[(b * NN + n) * 3 + 1];
    int cz = cent[(b * NN + n) * 3 + 2];
    int sx = max(cx - 7, 0), ex = min(cx + 8, 96);
    int sy = max(cy - 7, 0), ey = min(cy + 8, 96);
    int sz = max(cz - 7, 0), ez = min(cz + 8, 96);
    const float* xb = x + (size_t)(b * C_ + c) * (96 * 96 * 96);
    unsigned short* Arow = Af + (size_t)m * K_TOT + (size_t)c * PK;
    for (int k = threadIdx.x; k < PK; k += blockDim.x) {
        int iz = k % 15;
        int t  = k / 15;
        int iy = t % 15;
        int ix = t / 15;
        int hx = sx + ix, wy = sy + iy, dz = sz + iz;
        float v = 0.0f;
        if (hx < ex && wy < ey && dz < ez)
            v = xb[(hx * 96 + wy) * 96 + dz];
        Arow[k] = f2bf(v);
    }
}

// ---------------- kernel 2: split-K GEMM, F-tile 256, dbuf LDS + counted vmcnt ---
// Grid (x=64 chunks, y=4 f-tiles): dispatch id = by*64+bx === s (mod 8), so the
// 4 fx-blocks of chunk s land on one XCD (round-robin dispatch) -> together they
// consume full 4KB W rows and share the chunk's A-slice in that XCD's L2.
// 1 block/CU; per wave per step: 8 W + 2 A global_load_lds; steady wait vmcnt(10).
__global__ __launch_bounds__(256, 1) void gemm_kernel(const unsigned short* __restrict__ Af,
                                                      const float* __restrict__ W,
                                                      float* __restrict__ partial,
                                                      int CS) {
    __shared__ __align__(16) unsigned char smem[2 * WBUF + 2 * ABUF];  // 82,432 B
    int s  = blockIdx.x;                       // K-chunk (0..63)
    int fx = blockIdx.y;                       // 0..3 : 256-col F tile
    int st0 = s * CS;
    int st1 = min(st0 + CS, KSTEPS);
    int f0  = fx * 256;

    int tid  = (int)threadIdx.x;
    int wave = tid >> 6, lane = tid & 63;
    int fr = lane & 15, lgrp = lane >> 4;

    f32x4 acc[8][4];
#pragma unroll
    for (int i = 0; i < 8; ++i)
#pragma unroll
        for (int j = 0; j < 4; ++j) acc[i][j] = (f32x4)(0.0f);

    // per wave per step: 8 W half-pairs (1KB rows) + 2 A fragment-gathers
    auto STAGE = [&](int buf, int st) {
        int k0 = st << 5;
        unsigned char* wb = smem + buf * WBUF;
        const float* wsrc = W + (size_t)k0 * F_TOT + f0 + (lane << 2);
#pragma unroll
        for (int r = 0; r < 8; ++r) {
            int row = r * 4 + wave;            // 0..31
            async_copy16(wb + (row >> 1) * WPAIR + (row & 1) * 1024,
                         wsrc + (size_t)row * F_TOT);
        }
        unsigned char* ab = smem + 2 * WBUF + buf * ABUF;
        const unsigned short* ag = Af + (size_t)fr * K_TOT + k0 + lgrp * 8;
#pragma unroll
        for (int i = 0; i < 2; ++i) {
            int mt = wave * 2 + i;
            async_copy16(ab + mt * 1024, ag + (size_t)(mt * 16) * K_TOT);
        }
    };

    auto COMPUTE = [&](int buf) {
        const unsigned char* ab = smem + 2 * WBUF + buf * ABUF;
        const unsigned char* wb = smem + buf * WBUF;
        bf16x8 afrag[8];
#pragma unroll
        for (int mt = 0; mt < 8; ++mt)      // ds_read_b128, lane-consecutive 16B
            afrag[mt] = *reinterpret_cast<const bf16x8*>(ab + mt * 1024 + lane * 16);
#pragma unroll
        for (int ft = 0; ft < 4; ++ft) {
            int fl4 = (wave * 64 + ft * 16 + fr) * 4;
            float wv[8];
#pragma unroll
            for (int j = 0; j < 8; ++j) {
                int row = lgrp * 8 + j;
                wv[j] = *reinterpret_cast<const float*>(
                            wb + (row >> 1) * WPAIR + (row & 1) * 1024 + fl4);
            }
            ushort8 bt;
#pragma unroll
            for (int j = 0; j < 8; ++j) bt[j] = f2bf(wv[j]);
            bf16x8 bfrag = __builtin_bit_cast(bf16x8, bt);
#pragma unroll
            for (int mt = 0; mt < 8; ++mt)
                acc[mt][ft] = __builtin_amdgcn_mfma_f32_16x16x32_bf16(afrag[mt], bfrag, acc[mt][ft], 0, 0, 0);
        }
    };

    int cur = 0;
    STAGE(0, st0);
    for (int t = st0; t < st1 - 1; ++t) {
        STAGE(cur ^ 1, t + 1);
        asm volatile("s_waitcnt vmcnt(10)" ::: "memory");  // stage(t) done; stage(t+1) in flight
        __builtin_amdgcn_s_barrier();
        COMPUTE(cur);
        __builtin_amdgcn_s_barrier();
        cur ^= 1;
    }
    asm volatile("s_waitcnt vmcnt(0)" ::: "memory");
    __builtin_amdgcn_s_barrier();
    COMPUTE(cur);

    // --- write partials: D row = lgrp*4 + r, col = fr (m89-verified mapping) ---
    float* pout = partial + (size_t)s * (M_TOT * F_TOT);
#pragma unroll
    for (int mt = 0; mt < 8; ++mt) {
        int mbase = mt * 16 + lgrp * 4;
#pragma unroll
        for (int ft = 0; ft < 4; ++ft) {
            int f = f0 + wave * 64 + ft * 16 + fr;
#pragma unroll
            for (int r = 0; r < 4; ++r)
                pout[(size_t)(mbase + r) * F_TOT + f] = acc[mt][ft][r];
        }
    }
}

// ---------------- kernel 3: split-K reduce + bias (vectorized) ----------------
__global__ void reduce_kernel(const float* __restrict__ partial,
                              const float* __restrict__ bias,
                              float* __restrict__ out, int S) {
    int i4 = (blockIdx.x * blockDim.x + threadIdx.x) * 4;
    if (i4 >= M_TOT * F_TOT) return;
    f32x4 a = *reinterpret_cast<const f32x4*>(bias + (i4 & (F_TOT - 1)));
    for (int s = 0; s < S; ++s)
        a += *reinterpret_cast<const f32x4*>(partial + (size_t)s * (M_TOT * F_TOT) + i4);
    *reinterpret_cast<f32x4*>(out + i4) = a;
}

extern "C" void kernel_launch(void* const* d_in, const int* in_sizes, int n_in,
                              void* d_out, int out_size, void* d_ws, size_t ws_size,
                              hipStream_t stream) {
    const float* x    = (const float*)d_in[0];
    const int*   cent = (const int*)d_in[1];
    const float* W    = (const float*)d_in[2];
    const float* bias = (const float*)d_in[3];
    float* out = (float*)d_out;

    unsigned short* Af = (unsigned short*)d_ws;
    size_t Af_bytes = (size_t)M_TOT * K_TOT * 2;                 // 27,648,000
    float* partial = (float*)((char*)d_ws + Af_bytes);

    size_t avail = ws_size > Af_bytes ? ws_size - Af_bytes : 0;
    int S = (int)(avail / ((size_t)M_TOT * F_TOT * 4));
    if (S > 64) S = 64;                   // grid (64,4) = 256 blocks = 1/CU
    if (S < 1)  S = 1;
    int CS = (KSTEPS + S - 1) / S;        // 53 for S=64
    S = (KSTEPS + CS - 1) / CS;           // 64 (last chunk = 36 steps)

    extract_kernel<<<dim3(M_TOT, C_), 256, 0, stream>>>(x, cent, Af);
    gemm_kernel<<<dim3(S, 4), 256, 0, stream>>>(Af, W, partial, CS);
    reduce_kernel<<<dim3((M_TOT * F_TOT + 1023) / 1024, 1, 1), 256, 0, stream>>>(partial, bias, out, S);
}